// Round 5
// baseline (825.668 us; speedup 1.0000x reference)
//
#include <hip/hip_runtime.h>
#include <stdint.h>

#define N_NODES 100000
#define N_EDGES 600000
#define HID 128
#define OUT_C 64
#define NELEMS 12800000      // 100000*128
#define BN_EPS 1e-5f

// ---------------- threefry2x32 (matches JAX) ----------------
__device__ __host__ __forceinline__ void threefry2x32(uint32_t k0, uint32_t k1,
                                                      uint32_t x0, uint32_t x1,
                                                      uint32_t& o0, uint32_t& o1) {
  uint32_t ks0 = k0, ks1 = k1, ks2 = k0 ^ k1 ^ 0x1BD11BDAu;
  x0 += ks0; x1 += ks1;
#define TFR(r) { x0 += x1; x1 = (x1 << (r)) | (x1 >> (32 - (r))); x1 ^= x0; }
  TFR(13) TFR(15) TFR(26) TFR(6)
  x0 += ks1; x1 += ks2 + 1u;
  TFR(17) TFR(29) TFR(16) TFR(24)
  x0 += ks2; x1 += ks0 + 2u;
  TFR(13) TFR(15) TFR(26) TFR(6)
  x0 += ks0; x1 += ks1 + 3u;
  TFR(17) TFR(29) TFR(16) TFR(24)
  x0 += ks1; x1 += ks2 + 4u;
  TFR(13) TFR(15) TFR(26) TFR(6)
  x0 += ks2; x1 += ks0 + 5u;
#undef TFR
  o0 = x0; o1 = x1;
}

// JAX threefry_partitionable random_bits for flat index i: out0^out1 of threefry(key,(0,i))
__device__ __forceinline__ uint32_t jax_bits32(uint32_t k0, uint32_t k1, uint32_t i) {
  uint32_t b0, b1;
  threefry2x32(k0, k1, 0u, i, b0, b1);
  return b0 ^ b1;
}

// ---------------- plain GEMM (layer 1): O[r][c] = sum_k A[r][k]*W[k][c]
__global__ __launch_bounds__(256) void gemm_nk128(const float* __restrict__ A,
                                                  const float* __restrict__ W,
                                                  float* __restrict__ O) {
  __shared__ __align__(16) float Wl[64 * 128];
  __shared__ __align__(16) float At[64 * 36];
  const int tid = threadIdx.x;
  const int lane = tid & 63;
  const int wv = tid >> 6;
  const int rbase = blockIdx.x * 32;
  const int r0 = wv * 8;

  float acc0[8], acc1[8];
#pragma unroll
  for (int i = 0; i < 8; ++i) { acc0[i] = 0.f; acc1[i] = 0.f; }

  for (int kh = 0; kh < 2; ++kh) {
    const float4* Wsrc = (const float4*)(W + kh * 64 * 128);
    float4* Wd = (float4*)Wl;
#pragma unroll
    for (int i = 0; i < 8; ++i) Wd[tid + i * 256] = Wsrc[tid + i * 256];
#pragma unroll
    for (int i = 0; i < 2; ++i) {
      int f4 = tid + i * 256;
      int row = f4 >> 4;
      int kq = f4 & 15;
      float4 v = *(const float4*)(A + (size_t)(rbase + row) * 128 + kh * 64 + kq * 4);
      At[(kq * 4 + 0) * 36 + row] = v.x;
      At[(kq * 4 + 1) * 36 + row] = v.y;
      At[(kq * 4 + 2) * 36 + row] = v.z;
      At[(kq * 4 + 3) * 36 + row] = v.w;
    }
    __syncthreads();
#pragma unroll 4
    for (int k = 0; k < 64; ++k) {
      float4 alo = *(const float4*)&At[k * 36 + r0];
      float4 ahi = *(const float4*)&At[k * 36 + r0 + 4];
      float2 w = *(const float2*)&Wl[k * 128 + lane * 2];
      acc0[0] += alo.x * w.x; acc1[0] += alo.x * w.y;
      acc0[1] += alo.y * w.x; acc1[1] += alo.y * w.y;
      acc0[2] += alo.z * w.x; acc1[2] += alo.z * w.y;
      acc0[3] += alo.w * w.x; acc1[3] += alo.w * w.y;
      acc0[4] += ahi.x * w.x; acc1[4] += ahi.x * w.y;
      acc0[5] += ahi.y * w.x; acc1[5] += ahi.y * w.y;
      acc0[6] += ahi.z * w.x; acc1[6] += ahi.z * w.y;
      acc0[7] += ahi.w * w.x; acc1[7] += ahi.w * w.y;
    }
    __syncthreads();
  }
#pragma unroll
  for (int i = 0; i < 8; ++i) {
    int row = rbase + r0 + i;
    float2 v = make_float2(acc0[i], acc1[i]);
    *(float2*)(O + (size_t)row * 128 + lane * 2) = v;
  }
}

// ---------------- fused GEMM (layers 2,3): A-staging applies BN+ReLU (writes X)
// then dropout (threefry) and uses the dropped values as the GEMM A operand.
__global__ __launch_bounds__(256) void gemm_fused(const float* __restrict__ AGG,
                                                  const float* __restrict__ sums,
                                                  const float* __restrict__ g,
                                                  const float* __restrict__ bt,
                                                  const float* __restrict__ W,
                                                  float* __restrict__ X,
                                                  float* __restrict__ O,
                                                  uint32_t k0, uint32_t k1) {
  __shared__ __align__(16) float Wl[64 * 128];
  __shared__ __align__(16) float At[64 * 36];
  const int tid = threadIdx.x;
  const int lane = tid & 63;
  const int wv = tid >> 6;
  const int rbase = blockIdx.x * 32;
  const int r0 = wv * 8;

  float acc0[8], acc1[8];
#pragma unroll
  for (int i = 0; i < 8; ++i) { acc0[i] = 0.f; acc1[i] = 0.f; }

  for (int kh = 0; kh < 2; ++kh) {
    const float4* Wsrc = (const float4*)(W + kh * 64 * 128);
    float4* Wd = (float4*)Wl;
#pragma unroll
    for (int i = 0; i < 8; ++i) Wd[tid + i * 256] = Wsrc[tid + i * 256];
#pragma unroll
    for (int i = 0; i < 2; ++i) {
      int f4 = tid + i * 256;
      int row = f4 >> 4;
      int kq = f4 & 15;
      int c0 = kh * 64 + kq * 4;
      int grow = rbase + row;
      float4 a = *(const float4*)(AGG + (size_t)grow * 128 + c0);
      float y[4], hd[4];
#pragma unroll
      for (int jj = 0; jj < 4; ++jj) {
        int c = c0 + jj;
        float mu = sums[c] * (1.0f / N_NODES);
        float var = fmaxf(sums[128 + c] * (1.0f / N_NODES) - mu * mu, 0.f);
        float inv = rsqrtf(var + BN_EPS);
        float av = ((const float*)&a)[jj];
        float yv = fmaxf(g[c] * (av - mu) * inv + bt[c], 0.f);
        uint32_t bits = jax_bits32(k0, k1, (uint32_t)(grow * 128 + c));
        y[jj] = yv;
        hd[jj] = (bits & 0x80000000u) ? 0.f : 2.f * yv;
      }
      *(float4*)(X + (size_t)grow * 128 + c0) = *(float4*)y;
      At[(c0 - kh * 64 + 0) * 36 + row] = hd[0];
      At[(c0 - kh * 64 + 1) * 36 + row] = hd[1];
      At[(c0 - kh * 64 + 2) * 36 + row] = hd[2];
      At[(c0 - kh * 64 + 3) * 36 + row] = hd[3];
    }
    __syncthreads();
#pragma unroll 4
    for (int k = 0; k < 64; ++k) {
      float4 alo = *(const float4*)&At[k * 36 + r0];
      float4 ahi = *(const float4*)&At[k * 36 + r0 + 4];
      float2 w = *(const float2*)&Wl[k * 128 + lane * 2];
      acc0[0] += alo.x * w.x; acc1[0] += alo.x * w.y;
      acc0[1] += alo.y * w.x; acc1[1] += alo.y * w.y;
      acc0[2] += alo.z * w.x; acc1[2] += alo.z * w.y;
      acc0[3] += alo.w * w.x; acc1[3] += alo.w * w.y;
      acc0[4] += ahi.x * w.x; acc1[4] += ahi.x * w.y;
      acc0[5] += ahi.y * w.x; acc1[5] += ahi.y * w.y;
      acc0[6] += ahi.z * w.x; acc1[6] += ahi.z * w.y;
      acc0[7] += ahi.w * w.x; acc1[7] += ahi.w * w.y;
    }
    __syncthreads();
  }
#pragma unroll
  for (int i = 0; i < 8; ++i) {
    int row = rbase + r0 + i;
    float2 v = make_float2(acc0[i], acc1[i]);
    *(float2*)(O + (size_t)row * 128 + lane * 2) = v;
  }
}

// ---------------- CSR build ----------------
__global__ __launch_bounds__(256) void csr_count(const int* __restrict__ ei,
                                                 int* __restrict__ cnt) {
  int e = blockIdx.x * 256 + threadIdx.x;
  if (e < N_EDGES) atomicAdd(&cnt[ei[e + N_EDGES]], 1);
}

__global__ __launch_bounds__(256) void scan_blocks(int* __restrict__ cnt,
                                                   int* __restrict__ bsum) {
  __shared__ int tmp[256];
  int tid = threadIdx.x;
  int i = blockIdx.x * 256 + tid;
  int v = (i < N_NODES) ? cnt[i] : 0;
  tmp[tid] = v;
  __syncthreads();
  for (int off = 1; off < 256; off <<= 1) {
    int t = (tid >= off) ? tmp[tid - off] : 0;
    __syncthreads();
    if (tid >= off) tmp[tid] += t;
    __syncthreads();
  }
  if (i < N_NODES) cnt[i] = tmp[tid] - v;
  if (tid == 255) bsum[blockIdx.x] = tmp[255];
}

__global__ __launch_bounds__(512) void scan_bsum(int* __restrict__ bsum, int nb) {
  __shared__ int tmp[512];
  int tid = threadIdx.x;
  int v = (tid < nb) ? bsum[tid] : 0;
  tmp[tid] = v;
  __syncthreads();
  for (int off = 1; off < 512; off <<= 1) {
    int t = (tid >= off) ? tmp[tid - off] : 0;
    __syncthreads();
    if (tid >= off) tmp[tid] += t;
    __syncthreads();
  }
  if (tid < nb) bsum[tid] = tmp[tid] - v;
}

__global__ __launch_bounds__(256) void add_offsets(int* __restrict__ cnt,
                                                   const int* __restrict__ bsum,
                                                   int* __restrict__ row_ptr) {
  int i = blockIdx.x * 256 + threadIdx.x;
  if (i < N_NODES) {
    int r = cnt[i] + bsum[blockIdx.x];
    row_ptr[i] = r;
    cnt[i] = r;
  }
  if (i == 0) row_ptr[N_NODES] = N_EDGES;
}

__global__ __launch_bounds__(256) void csr_fill(const int* __restrict__ ei,
                                                const float* __restrict__ ew,
                                                int* __restrict__ cursor,
                                                int* __restrict__ srcs,
                                                float* __restrict__ wcsr) {
  int e = blockIdx.x * 256 + threadIdx.x;
  if (e < N_EDGES) {
    int d = ei[e + N_EDGES];
    int p = atomicAdd(&cursor[d], 1);
    srcs[p] = ei[e];
    wcsr[p] = ew[e];
  }
}

// ---------------- gather aggregation + fused BN partial stats
// block = 1024 threads = 16 waves; each HALF-wave (32 lanes x float4) owns one node.
// grid = 3125 blocks * 32 nodes = 100000 exactly.
template <bool STATS>
__global__ __launch_bounds__(1024) void gather_agg(const float* __restrict__ H,
                                                   const int* __restrict__ row_ptr,
                                                   const int* __restrict__ srcs,
                                                   const float* __restrict__ wcsr,
                                                   const float* __restrict__ bias,
                                                   float* __restrict__ AGG,
                                                   float* __restrict__ partials) {
  const int tid = threadIdx.x;
  const int half = tid >> 5;     // 0..31: node slot within block
  const int cq = tid & 31;       // channel quad: channels cq*4..cq*4+3
  const int node = blockIdx.x * 32 + half;

  float4 acc = *(const float4*)(bias + cq * 4);
  const int beg = row_ptr[node];
  const int end = row_ptr[node + 1];
  int j = beg;
  for (; j + 1 < end; j += 2) {
    int s0 = srcs[j], s1 = srcs[j + 1];
    float w0 = wcsr[j], w1 = wcsr[j + 1];
    float4 v0 = *(const float4*)(H + (size_t)s0 * 128 + cq * 4);
    float4 v1 = *(const float4*)(H + (size_t)s1 * 128 + cq * 4);
    acc.x += w0 * v0.x + w1 * v1.x;
    acc.y += w0 * v0.y + w1 * v1.y;
    acc.z += w0 * v0.z + w1 * v1.z;
    acc.w += w0 * v0.w + w1 * v1.w;
  }
  if (j < end) {
    int s = srcs[j];
    float w = wcsr[j];
    float4 v = *(const float4*)(H + (size_t)s * 128 + cq * 4);
    acc.x += w * v.x;
    acc.y += w * v.y;
    acc.z += w * v.z;
    acc.w += w * v.w;
  }
  *(float4*)(AGG + (size_t)node * 128 + cq * 4) = acc;

  if (STATS) {
    __shared__ float st[256];        // [0..127]=sum, [128..255]=sumsq
    if (tid < 256) st[tid] = 0.f;
    __syncthreads();
    unsafeAtomicAdd(&st[cq * 4 + 0], acc.x);
    unsafeAtomicAdd(&st[cq * 4 + 1], acc.y);
    unsafeAtomicAdd(&st[cq * 4 + 2], acc.z);
    unsafeAtomicAdd(&st[cq * 4 + 3], acc.w);
    unsafeAtomicAdd(&st[128 + cq * 4 + 0], acc.x * acc.x);
    unsafeAtomicAdd(&st[128 + cq * 4 + 1], acc.y * acc.y);
    unsafeAtomicAdd(&st[128 + cq * 4 + 2], acc.z * acc.z);
    unsafeAtomicAdd(&st[128 + cq * 4 + 3], acc.w * acc.w);
    __syncthreads();
    if (tid < 256) partials[blockIdx.x * 256 + tid] = st[tid];
  }
}

// sum 3125 partial blocks of 256 floats into sums[256]
__global__ __launch_bounds__(256) void reduce_partials(const float* __restrict__ partials,
                                                       float* __restrict__ sums, int nblk) {
  float s = 0.f;
  for (int b = blockIdx.x; b < nblk; b += gridDim.x)
    s += partials[b * 256 + threadIdx.x];
  unsafeAtomicAdd(&sums[threadIdx.x], s);
}

// ---------------- jk = max(x1,x2,x3); OUT = log_softmax(jk @ Wf + bf)
// 64 rows/block; wave owns 16 contiguous rows; lane = output col.
__global__ __launch_bounds__(256) void jk_final(const float* __restrict__ X1,
                                                const float* __restrict__ X2,
                                                const float* __restrict__ X3,
                                                const float* __restrict__ Wf,
                                                const float* __restrict__ bf,
                                                float* __restrict__ OUT) {
  __shared__ __align__(16) float Wl[128 * 64];     // 32KB
  __shared__ __align__(16) float Jl[64][128];      // 32KB
  int tid = threadIdx.x;
  int lane = tid & 63;
  int wv = tid >> 6;
  int rbase = blockIdx.x * 64;
  {
    const float4* ws = (const float4*)Wf;
    float4* wd = (float4*)Wl;
#pragma unroll
    for (int i = 0; i < 8; ++i) wd[tid + i * 256] = ws[tid + i * 256];
  }
#pragma unroll
  for (int i = 0; i < 8; ++i) {
    int f4 = tid + i * 256;       // 2048 float4
    int row = f4 >> 5;            // 32 float4 per row
    int q = f4 & 31;
    int grow = rbase + row;
    float4 m = make_float4(0.f, 0.f, 0.f, 0.f);
    if (grow < N_NODES) {
      size_t off = (size_t)grow * 128 + q * 4;
      float4 a = *(const float4*)(X1 + off);
      float4 b = *(const float4*)(X2 + off);
      float4 c = *(const float4*)(X3 + off);
      m.x = fmaxf(fmaxf(a.x, b.x), c.x);
      m.y = fmaxf(fmaxf(a.y, b.y), c.y);
      m.z = fmaxf(fmaxf(a.z, b.z), c.z);
      m.w = fmaxf(fmaxf(a.w, b.w), c.w);
    }
    *(float4*)&Jl[row][q * 4] = m;
  }
  __syncthreads();
  float acc[16];
  float bv = bf[lane];
#pragma unroll
  for (int j = 0; j < 16; ++j) acc[j] = bv;
  const int r0 = wv * 16;
#pragma unroll 2
  for (int k = 0; k < 128; k += 4) {
    float w0 = Wl[(k + 0) * 64 + lane];
    float w1 = Wl[(k + 1) * 64 + lane];
    float w2 = Wl[(k + 2) * 64 + lane];
    float w3 = Wl[(k + 3) * 64 + lane];
#pragma unroll
    for (int j = 0; j < 16; ++j) {
      float4 jv = *(const float4*)&Jl[r0 + j][k];
      acc[j] += jv.x * w0 + jv.y * w1 + jv.z * w2 + jv.w * w3;
    }
  }
#pragma unroll
  for (int j = 0; j < 16; ++j) {
    float v = acc[j];
    float m = v;
#pragma unroll
    for (int s = 32; s > 0; s >>= 1) m = fmaxf(m, __shfl_xor(m, s));
    float e = expf(v - m);
    float sum = e;
#pragma unroll
    for (int s = 32; s > 0; s >>= 1) sum += __shfl_xor(sum, s);
    int row = rbase + r0 + j;
    if (row < N_NODES)
      OUT[(size_t)row * 64 + lane] = v - m - logf(sum);
  }
}

extern "C" void kernel_launch(void* const* d_in, const int* in_sizes, int n_in,
                              void* d_out, int out_size, void* d_ws, size_t ws_size,
                              hipStream_t stream) {
  const float* x   = (const float*)d_in[0];
  const int*   ei  = (const int*)d_in[1];
  const float* ew  = (const float*)d_in[2];
  const float* W1  = (const float*)d_in[3];
  const float* b1  = (const float*)d_in[4];
  const float* W2  = (const float*)d_in[5];
  const float* b2  = (const float*)d_in[6];
  const float* W3  = (const float*)d_in[7];
  const float* b3  = (const float*)d_in[8];
  const float* g1  = (const float*)d_in[9];
  const float* bt1 = (const float*)d_in[10];
  const float* g2  = (const float*)d_in[11];
  const float* bt2 = (const float*)d_in[12];
  const float* Wf  = (const float*)d_in[13];
  const float* bfb = (const float*)d_in[14];
  float* out = (float*)d_out;

  float* B0 = (float*)d_ws;
  float* B1 = B0 + NELEMS;
  float* B2 = B1 + NELEMS;
  float* B3 = B2 + NELEMS;
  float* sums = B3 + NELEMS;               // 512 floats: [0..255]=layer1, [256..511]=layer2
  int* cursor = (int*)(sums + 512);        // N_NODES
  int* row_ptr = cursor + N_NODES;         // N_NODES+1
  int* bsum = row_ptr + N_NODES + 1;       // 512
  int* srcs = bsum + 512;                  // N_EDGES
  float* wcsr = (float*)(srcs + N_EDGES);  // N_EDGES
  float* partials = wcsr + N_EDGES;        // 3125*256 floats (3.2MB)
  float* sums1 = sums;
  float* sums2 = sums + 256;

  // JAX partitionable split of key(42)=(0,42): k_i = threefry(key, (0,i)) full pair
  uint32_t k1_0, k1_1, k2_0, k2_1;
  threefry2x32(0u, 42u, 0u, 0u, k1_0, k1_1);
  threefry2x32(0u, 42u, 0u, 1u, k2_0, k2_1);

  const int GEMM_GRID = N_NODES / 32;              // 3125
  const int EDGE_GRID = (N_EDGES + 255) / 256;     // 2344
  const int NODE_GRID = (N_NODES + 255) / 256;     // 391
  const int AGG_GRID  = N_NODES / 32;              // 3125 (1024-thread blocks)
  const int RED_GRID  = 16;
  const int FINAL_GRID = (N_NODES + 63) / 64;      // 1563

  // ---- CSR build (reused by all 3 layers)
  hipMemsetAsync(cursor, 0, N_NODES * sizeof(int), stream);
  hipMemsetAsync(sums, 0, 512 * sizeof(float), stream);
  csr_count<<<EDGE_GRID, 256, 0, stream>>>(ei, cursor);
  scan_blocks<<<NODE_GRID, 256, 0, stream>>>(cursor, bsum);
  scan_bsum<<<1, 512, 0, stream>>>(bsum, NODE_GRID);
  add_offsets<<<NODE_GRID, 256, 0, stream>>>(cursor, bsum, row_ptr);
  csr_fill<<<EDGE_GRID, 256, 0, stream>>>(ei, ew, cursor, srcs, wcsr);

  // ---- layer 1: P1 = x@W1 ; AGG1 = gather(P1)+b1 (partial stats -> sums1)
  gemm_nk128<<<GEMM_GRID, 256, 0, stream>>>(x, W1, B0);
  gather_agg<true><<<AGG_GRID, 1024, 0, stream>>>(B0, row_ptr, srcs, wcsr, b1, B1, partials);
  reduce_partials<<<RED_GRID, 256, 0, stream>>>(partials, sums1, AGG_GRID);
  // ---- layer 2: fused BN1+ReLU (-> X1=B2) + dropout(k1) + GEMM W2 -> P2=B0
  gemm_fused<<<GEMM_GRID, 256, 0, stream>>>(B1, sums1, g1, bt1, W2, B2, B0, k1_0, k1_1);
  gather_agg<true><<<AGG_GRID, 1024, 0, stream>>>(B0, row_ptr, srcs, wcsr, b2, B1, partials);
  reduce_partials<<<RED_GRID, 256, 0, stream>>>(partials, sums2, AGG_GRID);
  // ---- layer 3: fused BN2+ReLU (-> X2=B3) + dropout(k2) + GEMM W3 -> P3=B0
  gemm_fused<<<GEMM_GRID, 256, 0, stream>>>(B1, sums2, g2, bt2, W3, B3, B0, k2_0, k2_1);
  gather_agg<false><<<AGG_GRID, 1024, 0, stream>>>(B0, row_ptr, srcs, wcsr, b3, B1, nullptr);
  // ---- JK max + final linear + log_softmax
  jk_final<<<FINAL_GRID, 256, 0, stream>>>(B2, B3, B1, Wf, bfb, out);
}

// Round 6
// 622.303 us; speedup vs baseline: 1.3268x; 1.3268x over previous
//
#include <hip/hip_runtime.h>
#include <stdint.h>

#define N_NODES 100000
#define N_EDGES 600000
#define HID 128
#define OUT_C 64
#define NELEMS 12800000      // 100000*128
#define BN_EPS 1e-5f

// ---------------- threefry2x32 (matches JAX) ----------------
__device__ __host__ __forceinline__ void threefry2x32(uint32_t k0, uint32_t k1,
                                                      uint32_t x0, uint32_t x1,
                                                      uint32_t& o0, uint32_t& o1) {
  uint32_t ks0 = k0, ks1 = k1, ks2 = k0 ^ k1 ^ 0x1BD11BDAu;
  x0 += ks0; x1 += ks1;
#define TFR(r) { x0 += x1; x1 = (x1 << (r)) | (x1 >> (32 - (r))); x1 ^= x0; }
  TFR(13) TFR(15) TFR(26) TFR(6)
  x0 += ks1; x1 += ks2 + 1u;
  TFR(17) TFR(29) TFR(16) TFR(24)
  x0 += ks2; x1 += ks0 + 2u;
  TFR(13) TFR(15) TFR(26) TFR(6)
  x0 += ks0; x1 += ks1 + 3u;
  TFR(17) TFR(29) TFR(16) TFR(24)
  x0 += ks1; x1 += ks2 + 4u;
  TFR(13) TFR(15) TFR(26) TFR(6)
  x0 += ks2; x1 += ks0 + 5u;
#undef TFR
  o0 = x0; o1 = x1;
}

// JAX threefry_partitionable random_bits for flat index i: out0^out1 of threefry(key,(0,i))
__device__ __forceinline__ uint32_t jax_bits32(uint32_t k0, uint32_t k1, uint32_t i) {
  uint32_t b0, b1;
  threefry2x32(k0, k1, 0u, i, b0, b1);
  return b0 ^ b1;
}

// ---------------- plain GEMM (layer 1): O[r][c] = sum_k A[r][k]*W[k][c]
__global__ __launch_bounds__(256) void gemm_nk128(const float* __restrict__ A,
                                                  const float* __restrict__ W,
                                                  float* __restrict__ O) {
  __shared__ __align__(16) float Wl[64 * 128];
  __shared__ __align__(16) float At[64 * 36];
  const int tid = threadIdx.x;
  const int lane = tid & 63;
  const int wv = tid >> 6;
  const int rbase = blockIdx.x * 32;
  const int r0 = wv * 8;

  float acc0[8], acc1[8];
#pragma unroll
  for (int i = 0; i < 8; ++i) { acc0[i] = 0.f; acc1[i] = 0.f; }

  for (int kh = 0; kh < 2; ++kh) {
    const float4* Wsrc = (const float4*)(W + kh * 64 * 128);
    float4* Wd = (float4*)Wl;
#pragma unroll
    for (int i = 0; i < 8; ++i) Wd[tid + i * 256] = Wsrc[tid + i * 256];
#pragma unroll
    for (int i = 0; i < 2; ++i) {
      int f4 = tid + i * 256;
      int row = f4 >> 4;
      int kq = f4 & 15;
      float4 v = *(const float4*)(A + (size_t)(rbase + row) * 128 + kh * 64 + kq * 4);
      At[(kq * 4 + 0) * 36 + row] = v.x;
      At[(kq * 4 + 1) * 36 + row] = v.y;
      At[(kq * 4 + 2) * 36 + row] = v.z;
      At[(kq * 4 + 3) * 36 + row] = v.w;
    }
    __syncthreads();
#pragma unroll 4
    for (int k = 0; k < 64; ++k) {
      float4 alo = *(const float4*)&At[k * 36 + r0];
      float4 ahi = *(const float4*)&At[k * 36 + r0 + 4];
      float2 w = *(const float2*)&Wl[k * 128 + lane * 2];
      acc0[0] += alo.x * w.x; acc1[0] += alo.x * w.y;
      acc0[1] += alo.y * w.x; acc1[1] += alo.y * w.y;
      acc0[2] += alo.z * w.x; acc1[2] += alo.z * w.y;
      acc0[3] += alo.w * w.x; acc1[3] += alo.w * w.y;
      acc0[4] += ahi.x * w.x; acc1[4] += ahi.x * w.y;
      acc0[5] += ahi.y * w.x; acc1[5] += ahi.y * w.y;
      acc0[6] += ahi.z * w.x; acc1[6] += ahi.z * w.y;
      acc0[7] += ahi.w * w.x; acc1[7] += ahi.w * w.y;
    }
    __syncthreads();
  }
#pragma unroll
  for (int i = 0; i < 8; ++i) {
    int row = rbase + r0 + i;
    float2 v = make_float2(acc0[i], acc1[i]);
    *(float2*)(O + (size_t)row * 128 + lane * 2) = v;
  }
}

// ---------------- fused GEMM (layers 2,3): A-staging applies BN+ReLU (writes X)
// then dropout (threefry) and uses the dropped values as the GEMM A operand.
__global__ __launch_bounds__(256) void gemm_fused(const float* __restrict__ AGG,
                                                  const float* __restrict__ sums,
                                                  const float* __restrict__ g,
                                                  const float* __restrict__ bt,
                                                  const float* __restrict__ W,
                                                  float* __restrict__ X,
                                                  float* __restrict__ O,
                                                  uint32_t k0, uint32_t k1) {
  __shared__ __align__(16) float Wl[64 * 128];
  __shared__ __align__(16) float At[64 * 36];
  const int tid = threadIdx.x;
  const int lane = tid & 63;
  const int wv = tid >> 6;
  const int rbase = blockIdx.x * 32;
  const int r0 = wv * 8;

  float acc0[8], acc1[8];
#pragma unroll
  for (int i = 0; i < 8; ++i) { acc0[i] = 0.f; acc1[i] = 0.f; }

  for (int kh = 0; kh < 2; ++kh) {
    const float4* Wsrc = (const float4*)(W + kh * 64 * 128);
    float4* Wd = (float4*)Wl;
#pragma unroll
    for (int i = 0; i < 8; ++i) Wd[tid + i * 256] = Wsrc[tid + i * 256];
#pragma unroll
    for (int i = 0; i < 2; ++i) {
      int f4 = tid + i * 256;
      int row = f4 >> 4;
      int kq = f4 & 15;
      int c0 = kh * 64 + kq * 4;
      int grow = rbase + row;
      float4 a = *(const float4*)(AGG + (size_t)grow * 128 + c0);
      float y[4], hd[4];
#pragma unroll
      for (int jj = 0; jj < 4; ++jj) {
        int c = c0 + jj;
        float mu = sums[c] * (1.0f / N_NODES);
        float var = fmaxf(sums[128 + c] * (1.0f / N_NODES) - mu * mu, 0.f);
        float inv = rsqrtf(var + BN_EPS);
        float av = ((const float*)&a)[jj];
        float yv = fmaxf(g[c] * (av - mu) * inv + bt[c], 0.f);
        uint32_t bits = jax_bits32(k0, k1, (uint32_t)(grow * 128 + c));
        y[jj] = yv;
        hd[jj] = (bits & 0x80000000u) ? 0.f : 2.f * yv;
      }
      *(float4*)(X + (size_t)grow * 128 + c0) = *(float4*)y;
      At[(c0 - kh * 64 + 0) * 36 + row] = hd[0];
      At[(c0 - kh * 64 + 1) * 36 + row] = hd[1];
      At[(c0 - kh * 64 + 2) * 36 + row] = hd[2];
      At[(c0 - kh * 64 + 3) * 36 + row] = hd[3];
    }
    __syncthreads();
#pragma unroll 4
    for (int k = 0; k < 64; ++k) {
      float4 alo = *(const float4*)&At[k * 36 + r0];
      float4 ahi = *(const float4*)&At[k * 36 + r0 + 4];
      float2 w = *(const float2*)&Wl[k * 128 + lane * 2];
      acc0[0] += alo.x * w.x; acc1[0] += alo.x * w.y;
      acc0[1] += alo.y * w.x; acc1[1] += alo.y * w.y;
      acc0[2] += alo.z * w.x; acc1[2] += alo.z * w.y;
      acc0[3] += alo.w * w.x; acc1[3] += alo.w * w.y;
      acc0[4] += ahi.x * w.x; acc1[4] += ahi.x * w.y;
      acc0[5] += ahi.y * w.x; acc1[5] += ahi.y * w.y;
      acc0[6] += ahi.z * w.x; acc1[6] += ahi.z * w.y;
      acc0[7] += ahi.w * w.x; acc1[7] += ahi.w * w.y;
    }
    __syncthreads();
  }
#pragma unroll
  for (int i = 0; i < 8; ++i) {
    int row = rbase + r0 + i;
    float2 v = make_float2(acc0[i], acc1[i]);
    *(float2*)(O + (size_t)row * 128 + lane * 2) = v;
  }
}

// ---------------- CSR build ----------------
__global__ __launch_bounds__(256) void csr_count(const int* __restrict__ ei,
                                                 int* __restrict__ cnt) {
  int e = blockIdx.x * 256 + threadIdx.x;
  if (e < N_EDGES) atomicAdd(&cnt[ei[e + N_EDGES]], 1);
}

__global__ __launch_bounds__(256) void scan_blocks(int* __restrict__ cnt,
                                                   int* __restrict__ bsum) {
  __shared__ int tmp[256];
  int tid = threadIdx.x;
  int i = blockIdx.x * 256 + tid;
  int v = (i < N_NODES) ? cnt[i] : 0;
  tmp[tid] = v;
  __syncthreads();
  for (int off = 1; off < 256; off <<= 1) {
    int t = (tid >= off) ? tmp[tid - off] : 0;
    __syncthreads();
    if (tid >= off) tmp[tid] += t;
    __syncthreads();
  }
  if (i < N_NODES) cnt[i] = tmp[tid] - v;
  if (tid == 255) bsum[blockIdx.x] = tmp[255];
}

__global__ __launch_bounds__(512) void scan_bsum(int* __restrict__ bsum, int nb) {
  __shared__ int tmp[512];
  int tid = threadIdx.x;
  int v = (tid < nb) ? bsum[tid] : 0;
  tmp[tid] = v;
  __syncthreads();
  for (int off = 1; off < 512; off <<= 1) {
    int t = (tid >= off) ? tmp[tid - off] : 0;
    __syncthreads();
    if (tid >= off) tmp[tid] += t;
    __syncthreads();
  }
  if (tid < nb) bsum[tid] = tmp[tid] - v;
}

__global__ __launch_bounds__(256) void add_offsets(int* __restrict__ cnt,
                                                   const int* __restrict__ bsum,
                                                   int* __restrict__ row_ptr) {
  int i = blockIdx.x * 256 + threadIdx.x;
  if (i < N_NODES) {
    int r = cnt[i] + bsum[blockIdx.x];
    row_ptr[i] = r;
    cnt[i] = r;
  }
  if (i == 0) row_ptr[N_NODES] = N_EDGES;
}

// fill interleaved (src, w_bits) pairs
__global__ __launch_bounds__(256) void csr_fill(const int* __restrict__ ei,
                                                const float* __restrict__ ew,
                                                int* __restrict__ cursor,
                                                int2* __restrict__ edges) {
  int e = blockIdx.x * 256 + threadIdx.x;
  if (e < N_EDGES) {
    int d = ei[e + N_EDGES];
    int p = atomicAdd(&cursor[d], 1);
    edges[p] = make_int2(ei[e], __float_as_int(ew[e]));
  }
}

// ---------------- gather aggregation: AGG[n] = b + sum_{e->n} w_e * H[src_e]
// 1 node per 64-lane wave (lane owns channels 2l,2l+1); 4 waves/block; no barriers.
// Edge loop unrolled x4 with all row-loads issued before FMAs (4 loads in flight).
__global__ __launch_bounds__(256) void gather_agg(const float* __restrict__ H,
                                                  const int* __restrict__ row_ptr,
                                                  const int2* __restrict__ edges,
                                                  const float* __restrict__ bias,
                                                  float* __restrict__ AGG) {
  const int node = blockIdx.x * 4 + (threadIdx.x >> 6);
  const int lane = threadIdx.x & 63;
  float2 acc = *(const float2*)(bias + lane * 2);
  const int beg = row_ptr[node];
  const int end = row_ptr[node + 1];
  int j = beg;
  for (; j + 3 < end; j += 4) {
    int2 e0 = edges[j + 0];
    int2 e1 = edges[j + 1];
    int2 e2 = edges[j + 2];
    int2 e3 = edges[j + 3];
    float2 v0 = *(const float2*)(H + (size_t)e0.x * 128 + lane * 2);
    float2 v1 = *(const float2*)(H + (size_t)e1.x * 128 + lane * 2);
    float2 v2 = *(const float2*)(H + (size_t)e2.x * 128 + lane * 2);
    float2 v3 = *(const float2*)(H + (size_t)e3.x * 128 + lane * 2);
    float w0 = __int_as_float(e0.y), w1 = __int_as_float(e1.y);
    float w2 = __int_as_float(e2.y), w3 = __int_as_float(e3.y);
    acc.x += w0 * v0.x + w1 * v1.x + w2 * v2.x + w3 * v3.x;
    acc.y += w0 * v0.y + w1 * v1.y + w2 * v2.y + w3 * v3.y;
  }
  for (; j < end; ++j) {
    int2 e = edges[j];
    float2 v = *(const float2*)(H + (size_t)e.x * 128 + lane * 2);
    float w = __int_as_float(e.y);
    acc.x += w * v.x;
    acc.y += w * v.y;
  }
  *(float2*)(AGG + (size_t)node * 128 + lane * 2) = acc;
}

// ---------------- BN stats: per-channel sum & sumsq -> per-block partials
// 256 thr = 8 row-groups x 32 channel-quads; float4 per thread; reg accumulate.
__global__ __launch_bounds__(256) void bn_stats(const float* __restrict__ H,
                                                float* __restrict__ partials) {
  const int c4 = (threadIdx.x & 31) * 4;
  const int rg = threadIdx.x >> 5;              // 0..7
  float4 s = make_float4(0.f, 0.f, 0.f, 0.f);
  float4 q = make_float4(0.f, 0.f, 0.f, 0.f);
  for (int row = blockIdx.x * 8 + rg; row < N_NODES; row += gridDim.x * 8) {
    float4 v = *(const float4*)(H + (size_t)row * 128 + c4);
    s.x += v.x; s.y += v.y; s.z += v.z; s.w += v.w;
    q.x += v.x * v.x; q.y += v.y * v.y; q.z += v.z * v.z; q.w += v.w * v.w;
  }
  __shared__ float ls[8][256];
  *(float4*)&ls[rg][c4] = s;
  *(float4*)&ls[rg][128 + c4] = q;
  __syncthreads();
  float t = 0.f;
#pragma unroll
  for (int g = 0; g < 8; ++g) t += ls[g][threadIdx.x];
  partials[blockIdx.x * 256 + threadIdx.x] = t;
}

// sum nblk partial blocks of 256 floats into sums[256]
__global__ __launch_bounds__(256) void reduce_partials(const float* __restrict__ partials,
                                                       float* __restrict__ sums, int nblk) {
  float s = 0.f;
  for (int b = blockIdx.x; b < nblk; b += gridDim.x)
    s += partials[b * 256 + threadIdx.x];
  unsafeAtomicAdd(&sums[threadIdx.x], s);
}

// ---------------- jk = max(x1,x2,x3); OUT = log_softmax(jk @ Wf + bf)
// 64 rows/block; wave owns 16 contiguous rows; lane = output col.
__global__ __launch_bounds__(256) void jk_final(const float* __restrict__ X1,
                                                const float* __restrict__ X2,
                                                const float* __restrict__ X3,
                                                const float* __restrict__ Wf,
                                                const float* __restrict__ bf,
                                                float* __restrict__ OUT) {
  __shared__ __align__(16) float Wl[128 * 64];     // 32KB
  __shared__ __align__(16) float Jl[64][128];      // 32KB
  int tid = threadIdx.x;
  int lane = tid & 63;
  int wv = tid >> 6;
  int rbase = blockIdx.x * 64;
  {
    const float4* ws = (const float4*)Wf;
    float4* wd = (float4*)Wl;
#pragma unroll
    for (int i = 0; i < 8; ++i) wd[tid + i * 256] = ws[tid + i * 256];
  }
#pragma unroll
  for (int i = 0; i < 8; ++i) {
    int f4 = tid + i * 256;       // 2048 float4
    int row = f4 >> 5;            // 32 float4 per row
    int q = f4 & 31;
    int grow = rbase + row;
    float4 m = make_float4(0.f, 0.f, 0.f, 0.f);
    if (grow < N_NODES) {
      size_t off = (size_t)grow * 128 + q * 4;
      float4 a = *(const float4*)(X1 + off);
      float4 b = *(const float4*)(X2 + off);
      float4 c = *(const float4*)(X3 + off);
      m.x = fmaxf(fmaxf(a.x, b.x), c.x);
      m.y = fmaxf(fmaxf(a.y, b.y), c.y);
      m.z = fmaxf(fmaxf(a.z, b.z), c.z);
      m.w = fmaxf(fmaxf(a.w, b.w), c.w);
    }
    *(float4*)&Jl[row][q * 4] = m;
  }
  __syncthreads();
  float acc[16];
  float bv = bf[lane];
#pragma unroll
  for (int j = 0; j < 16; ++j) acc[j] = bv;
  const int r0 = wv * 16;
#pragma unroll 2
  for (int k = 0; k < 128; k += 4) {
    float w0 = Wl[(k + 0) * 64 + lane];
    float w1 = Wl[(k + 1) * 64 + lane];
    float w2 = Wl[(k + 2) * 64 + lane];
    float w3 = Wl[(k + 3) * 64 + lane];
#pragma unroll
    for (int j = 0; j < 16; ++j) {
      float4 jv = *(const float4*)&Jl[r0 + j][k];
      acc[j] += jv.x * w0 + jv.y * w1 + jv.z * w2 + jv.w * w3;
    }
  }
#pragma unroll
  for (int j = 0; j < 16; ++j) {
    float v = acc[j];
    float m = v;
#pragma unroll
    for (int s = 32; s > 0; s >>= 1) m = fmaxf(m, __shfl_xor(m, s));
    float e = expf(v - m);
    float sum = e;
#pragma unroll
    for (int s = 32; s > 0; s >>= 1) sum += __shfl_xor(sum, s);
    int row = rbase + r0 + j;
    if (row < N_NODES)
      OUT[(size_t)row * 64 + lane] = v - m - logf(sum);
  }
}

extern "C" void kernel_launch(void* const* d_in, const int* in_sizes, int n_in,
                              void* d_out, int out_size, void* d_ws, size_t ws_size,
                              hipStream_t stream) {
  const float* x   = (const float*)d_in[0];
  const int*   ei  = (const int*)d_in[1];
  const float* ew  = (const float*)d_in[2];
  const float* W1  = (const float*)d_in[3];
  const float* b1  = (const float*)d_in[4];
  const float* W2  = (const float*)d_in[5];
  const float* b2  = (const float*)d_in[6];
  const float* W3  = (const float*)d_in[7];
  const float* b3  = (const float*)d_in[8];
  const float* g1  = (const float*)d_in[9];
  const float* bt1 = (const float*)d_in[10];
  const float* g2  = (const float*)d_in[11];
  const float* bt2 = (const float*)d_in[12];
  const float* Wf  = (const float*)d_in[13];
  const float* bfb = (const float*)d_in[14];
  float* out = (float*)d_out;

  float* B0 = (float*)d_ws;
  float* B1 = B0 + NELEMS;
  float* B2 = B1 + NELEMS;
  float* B3 = B2 + NELEMS;
  float* sums = B3 + NELEMS;               // 512 floats: [0..255]=layer1, [256..511]=layer2
  int2* edges = (int2*)(sums + 512);       // N_EDGES int2 (8B-aligned)
  int* cursor = (int*)(edges + N_EDGES);   // N_NODES
  int* row_ptr = cursor + N_NODES;         // N_NODES+1
  int* bsum = row_ptr + N_NODES + 1;       // 512
  float* partials = (float*)(bsum + 512);  // 2048*256 floats (2MB)
  float* sums1 = sums;
  float* sums2 = sums + 256;

  // JAX partitionable split of key(42)=(0,42): k_i = threefry(key, (0,i)) full pair
  uint32_t k1_0, k1_1, k2_0, k2_1;
  threefry2x32(0u, 42u, 0u, 0u, k1_0, k1_1);
  threefry2x32(0u, 42u, 0u, 1u, k2_0, k2_1);

  const int GEMM_GRID = N_NODES / 32;              // 3125
  const int EDGE_GRID = (N_EDGES + 255) / 256;     // 2344
  const int NODE_GRID = (N_NODES + 255) / 256;     // 391
  const int AGG_GRID  = N_NODES / 4;               // 25000 (1 node/wave, 4 waves/block)
  const int STAT_GRID = 2048;
  const int RED_GRID  = 16;
  const int FINAL_GRID = (N_NODES + 63) / 64;      // 1563

  // ---- CSR build (reused by all 3 layers)
  hipMemsetAsync(cursor, 0, N_NODES * sizeof(int), stream);
  hipMemsetAsync(sums, 0, 512 * sizeof(float), stream);
  csr_count<<<EDGE_GRID, 256, 0, stream>>>(ei, cursor);
  scan_blocks<<<NODE_GRID, 256, 0, stream>>>(cursor, bsum);
  scan_bsum<<<1, 512, 0, stream>>>(bsum, NODE_GRID);
  add_offsets<<<NODE_GRID, 256, 0, stream>>>(cursor, bsum, row_ptr);
  csr_fill<<<EDGE_GRID, 256, 0, stream>>>(ei, ew, cursor, edges);

  // ---- layer 1: P1 = x@W1 ; AGG1 = gather(P1)+b1 ; stats1
  gemm_nk128<<<GEMM_GRID, 256, 0, stream>>>(x, W1, B0);
  gather_agg<<<AGG_GRID, 256, 0, stream>>>(B0, row_ptr, edges, b1, B1);
  bn_stats<<<STAT_GRID, 256, 0, stream>>>(B1, partials);
  reduce_partials<<<RED_GRID, 256, 0, stream>>>(partials, sums1, STAT_GRID);
  // ---- layer 2: fused BN1+ReLU (-> X1=B2) + dropout(k1) + GEMM W2 -> P2=B0
  gemm_fused<<<GEMM_GRID, 256, 0, stream>>>(B1, sums1, g1, bt1, W2, B2, B0, k1_0, k1_1);
  gather_agg<<<AGG_GRID, 256, 0, stream>>>(B0, row_ptr, edges, b2, B1);
  bn_stats<<<STAT_GRID, 256, 0, stream>>>(B1, partials);
  reduce_partials<<<RED_GRID, 256, 0, stream>>>(partials, sums2, STAT_GRID);
  // ---- layer 3: fused BN2+ReLU (-> X2=B3) + dropout(k2) + GEMM W3 -> P3=B0
  gemm_fused<<<GEMM_GRID, 256, 0, stream>>>(B1, sums2, g2, bt2, W3, B3, B0, k2_0, k2_1);
  gather_agg<<<AGG_GRID, 256, 0, stream>>>(B0, row_ptr, edges, b3, B1);
  // ---- JK max + final linear + log_softmax
  jk_final<<<FINAL_GRID, 256, 0, stream>>>(B2, B3, B1, Wf, bfb, out);
}